// Round 2
// baseline (1315.478 us; speedup 1.0000x reference)
//
#include <hip/hip_runtime.h>
#include <math.h>

namespace {
constexpr int Bn = 4, Cn = 3, Hn = 96, Wn = 96;
constexpr int HWn = Hn * Wn;          // 9216
constexpr int NP  = Bn * Cn;          // 12 (batch,class) pairs

// ws layout in 4-byte words:
constexpr int PC_OFF = 0;                     // pred_class [B*HW] int
constexpr int CNT_NA = Bn * HWn;              // n_a [NP]
constexpr int CNT_NB = CNT_NA + NP;           // n_b [NP]
constexpr int CNT_BA = CNT_NB + NP;           // boundary(pred) count / cursor [NP]
constexpr int CNT_BB = CNT_BA + NP;           // boundary(label) count / cursor [NP]
constexpr int SUM_F  = CNT_BB + NP;           // float sum_f [NP]
constexpr int SUM_B  = SUM_F + NP;            // float sum_b [NP]
constexpr int BA_OFF = SUM_B + NP;            // ba_list [NP][HW] packed (y<<8|x)
constexpr int BB_OFF = BA_OFF + NP * HWn;     // bb_list [NP][HW]
// total words = BB_OFF + NP*HW  ~= 258K words ~= 1.03 MB
}

// Kernel 1: zero counters/sums + per-pixel argmax over C classes.
__global__ void k_prep(const float* __restrict__ preds,
                       int* __restrict__ wi, float* __restrict__ wf) {
    int idx = blockIdx.x * blockDim.x + threadIdx.x;
    if (idx < 4 * NP) wi[CNT_NA + idx] = 0;          // zero the 4 counter arrays
    if (idx < 2 * NP) wf[SUM_F + idx] = 0.0f;        // zero the 2 sum arrays
    if (idx >= Bn * HWn) return;
    int b = idx / HWn, p = idx - b * HWn;
    const float* base = preds + (size_t)b * Cn * HWn + p;
    float best = base[0];
    int bi = 0;
#pragma unroll
    for (int c = 1; c < Cn; ++c) {
        float v = base[(size_t)c * HWn];
        if (v > best) { best = v; bi = c; }          // strict > == jnp.argmax first-max
    }
    wi[PC_OFF + idx] = bi;
}

// Kernel 2: membership counts + boundary detection + compact boundary lists.
__global__ void k_boundary(const int* __restrict__ labels, int* __restrict__ wi) {
    int idx = blockIdx.x * blockDim.x + threadIdx.x;
    if (idx >= NP * HWn) return;
    int pr = idx / HWn, p = idx - pr * HWn;
    int b = pr / Cn, c = pr - b * Cn;
    int y = p / Wn, x = p - y * Wn;
    const int* pc = wi + PC_OFF + b * HWn;
    const int* lb = labels + b * HWn;
    int a  = (pc[p] == c);
    int bm = (lb[p] == c);
    int packed = (y << 8) | x;
    if (a) {
        atomicAdd(&wi[CNT_NA + pr], 1);
        int cnt = 0;
        if (y > 0)      cnt += (pc[p - Wn] == c);
        if (y < Hn - 1) cnt += (pc[p + Wn] == c);
        if (x > 0)      cnt += (pc[p - 1] == c);
        if (x < Wn - 1) cnt += (pc[p + 1] == c);
        if (cnt < 4) {   // boundary = img*(5 - (1+cnt)) > 0  <=>  cnt < 4
            int pos = atomicAdd(&wi[CNT_BA + pr], 1);
            wi[BA_OFF + pr * HWn + pos] = packed;
        }
    }
    if (bm) {
        atomicAdd(&wi[CNT_NB + pr], 1);
        int cnt = 0;
        if (y > 0)      cnt += (lb[p - Wn] == c);
        if (y < Hn - 1) cnt += (lb[p + Wn] == c);
        if (x > 0)      cnt += (lb[p - 1] == c);
        if (x < Wn - 1) cnt += (lb[p + 1] == c);
        if (cnt < 4) {
            int pos = atomicAdd(&wi[CNT_BB + pr], 1);
            wi[BB_OFF + pr * HWn + pos] = packed;
        }
    }
}

// Kernel 3: per pair, sum over a_fwd pixels of min-dist to bb list, and
// over b_bwd pixels of min-dist to ba list. Integer d^2 inner loop (exact,
// matches reference's fp32-exact D2), one sqrtf per active pixel.
__global__ void k_mindist(const int* __restrict__ labels,
                          const int* __restrict__ wi, float* __restrict__ wf) {
    int pr = blockIdx.y;
    int p  = blockIdx.x * blockDim.x + threadIdx.x;   // < HW by grid construction
    int b = pr / Cn, c = pr - b * Cn;
    int a  = (wi[PC_OFF + b * HWn + p] == c);
    int bm = (labels[b * HWn + p] == c);
    int y = p / Wn, x = p - y * Wn;

    __shared__ int sc[256];

    // phase 1: a_fwd = a & !bm, min over bb_list
    {
        int nbb = wi[CNT_BB + pr];
        bool active = a && !bm && (nbb > 0);
        int md2 = 0x7fffffff;
        for (int base = 0; base < nbb; base += 256) {
            int n = min(256, nbb - base);
            __syncthreads();
            if ((int)threadIdx.x < n)
                sc[threadIdx.x] = wi[BB_OFF + pr * HWn + base + threadIdx.x];
            __syncthreads();
            if (active) {
                for (int j = 0; j < n; ++j) {
                    int q = sc[j];
                    int dy = y - (q >> 8);
                    int dx = x - (q & 255);
                    md2 = min(md2, dy * dy + dx * dx);
                }
            }
        }
        if (active) atomicAdd(&wf[SUM_F + pr], sqrtf((float)md2));
    }

    // phase 2: b_bwd = bm & !a, min over ba_list
    {
        int nba = wi[CNT_BA + pr];
        bool active = bm && !a && (nba > 0);
        int md2 = 0x7fffffff;
        for (int base = 0; base < nba; base += 256) {
            int n = min(256, nba - base);
            __syncthreads();
            if ((int)threadIdx.x < n)
                sc[threadIdx.x] = wi[BA_OFF + pr * HWn + base + threadIdx.x];
            __syncthreads();
            if (active) {
                for (int j = 0; j < n; ++j) {
                    int q = sc[j];
                    int dy = y - (q >> 8);
                    int dx = x - (q & 255);
                    md2 = min(md2, dy * dy + dx * dx);
                }
            }
        }
        if (active) atomicAdd(&wf[SUM_B + pr], sqrtf((float)md2));
    }
}

// Kernel 4: finalize 25 outputs (single thread; trivial work).
__global__ void k_final(const int* __restrict__ wi, const float* __restrict__ wf,
                        float* __restrict__ out) {
    if (blockIdx.x != 0 || threadIdx.x != 0) return;
    float hd[Bn][Cn];
    float failed[Cn] = {0.f, 0.f, 0.f};
    for (int pr = 0; pr < NP; ++pr) {
        int b = pr / Cn, c = pr - b * Cn;
        int na = wi[CNT_NA + pr];
        int nb = wi[CNT_NB + pr];
        float h;
        if (na == 0) {
            h = (Hn + Wn) / 4.0f;       // failure case
            failed[c] += 1.0f;
        } else {
            float hf = wf[SUM_F + pr] / fmaxf((float)na, 1.0f);
            float hb = wf[SUM_B + pr] / fmaxf((float)nb, 1.0f);
            h = fmaxf(hf, hb);
        }
        if (c == 0) h = 0.0f;           // IGNORE class
        hd[b][c] = h;
    }
    failed[0] = 0.0f;                   // IGNORE class
    for (int b = 0; b < Bn; ++b) {
        float* row = out + b * (Cn + 2);
        float s = 0.f;
        for (int c = 0; c < Cn; ++c) { row[c] = hd[b][c]; s += hd[b][c]; }
        row[Cn] = s / (float)Cn;                               // mean over all C
        row[Cn + 1] = (hd[b][0] + hd[b][1]) / (float)(Cn - 1); // mean over first C-1
    }
    float* Fc = out + Bn * (Cn + 2);
    float fs = 0.f;
    for (int c = 0; c < Cn; ++c) { Fc[c] = failed[c]; fs += failed[c]; }
    Fc[Cn] = fs / (float)Cn;
    Fc[Cn + 1] = (failed[1] + failed[2]) / (float)(Cn - 1);
}

extern "C" void kernel_launch(void* const* d_in, const int* in_sizes, int n_in,
                              void* d_out, int out_size, void* d_ws, size_t ws_size,
                              hipStream_t stream) {
    const float* preds  = (const float*)d_in[0];
    const int*   labels = (const int*)d_in[1];
    float* out = (float*)d_out;
    int*   wi = (int*)d_ws;
    float* wf = (float*)d_ws;

    // 1: zero + argmax  (B*HW = 36864 threads)
    k_prep<<<(Bn * HWn + 255) / 256, 256, 0, stream>>>(preds, wi, wf);
    // 2: boundary + lists  (NP*HW = 110592 threads)
    k_boundary<<<(NP * HWn + 255) / 256, 256, 0, stream>>>(labels, wi);
    // 3: min-distance sums  (grid: HW/256 x NP)
    dim3 g3(HWn / 256, NP);
    k_mindist<<<g3, 256, 0, stream>>>(labels, wi, wf);
    // 4: finalize
    k_final<<<1, 64, 0, stream>>>(wi, wf, out);
}

// Round 3
// 227.770 us; speedup vs baseline: 5.7755x; 5.7755x over previous
//
#include <hip/hip_runtime.h>
#include <math.h>

namespace {
constexpr int Bn = 4, Cn = 3, Hn = 96, Wn = 96;
constexpr int HWn = Hn * Wn;          // 9216 (divisible by 256 -> blocks never straddle a pair)
constexpr int NP  = Bn * Cn;          // 12 (batch,class) pairs
constexpr int STRIDE = 16;            // 64B per counter -> each atomic target owns a cacheline

// ws layout in 4-byte words:
constexpr int PC_OFF  = 0;                    // pred_class [B*HW] int
constexpr int CTR_OFF = Bn * HWn;             // 6 padded arrays x NP x STRIDE
constexpr int CTR_WORDS = 6 * NP * STRIDE;    // 1152 words
constexpr int BA_OFF  = CTR_OFF + CTR_WORDS;  // ba_list [NP][HW] packed (y<<8|x)
constexpr int BB_OFF  = BA_OFF + NP * HWn;    // bb_list [NP][HW]
// total ~= 259K words ~= 1.04 MB

__device__ __forceinline__ int CNT_NA_I(int pr) { return CTR_OFF + (0 * NP + pr) * STRIDE; }
__device__ __forceinline__ int CNT_NB_I(int pr) { return CTR_OFF + (1 * NP + pr) * STRIDE; }
__device__ __forceinline__ int CNT_BA_I(int pr) { return CTR_OFF + (2 * NP + pr) * STRIDE; }
__device__ __forceinline__ int CNT_BB_I(int pr) { return CTR_OFF + (3 * NP + pr) * STRIDE; }
__device__ __forceinline__ int SUM_F_I(int pr)  { return CTR_OFF + (4 * NP + pr) * STRIDE; }
__device__ __forceinline__ int SUM_B_I(int pr)  { return CTR_OFF + (5 * NP + pr) * STRIDE; }
}

// Kernel 1: zero counters/sums + per-pixel argmax over C classes.
__global__ void k_prep(const float* __restrict__ preds, int* __restrict__ wi) {
    int idx = blockIdx.x * blockDim.x + threadIdx.x;
    if (idx < CTR_WORDS) wi[CTR_OFF + idx] = 0;      // zeros ints AND f32 sums (bit pattern 0)
    if (idx >= Bn * HWn) return;
    int b = idx / HWn, p = idx - b * HWn;
    const float* base = preds + (size_t)b * Cn * HWn + p;
    float best = base[0];
    int bi = 0;
#pragma unroll
    for (int c = 1; c < Cn; ++c) {
        float v = base[(size_t)c * HWn];
        if (v > best) { best = v; bi = c; }          // strict > == jnp.argmax first-max
    }
    wi[PC_OFF + idx] = bi;
}

// Kernel 2: membership counts + boundary detection + compact boundary lists.
// All atomics wave-aggregated: ballot/popcount -> 1 atomic per wave per counter.
__global__ void k_boundary(const int* __restrict__ labels, int* __restrict__ wi) {
    int idx = blockIdx.x * blockDim.x + threadIdx.x;   // < NP*HW by grid construction
    int pr = idx / HWn, p = idx - pr * HWn;            // pr uniform per block (HW % 256 == 0)
    int b = pr / Cn, c = pr - b * Cn;
    int y = p / Wn, x = p - y * Wn;
    const int* pc = wi + PC_OFF + b * HWn;
    const int* lb = labels + b * HWn;
    int a  = (pc[p] == c);
    int bm = (lb[p] == c);
    int packed = (y << 8) | x;

    int bda = 0, bdb = 0;
    if (a) {
        int cnt = 0;
        if (y > 0)      cnt += (pc[p - Wn] == c);
        if (y < Hn - 1) cnt += (pc[p + Wn] == c);
        if (x > 0)      cnt += (pc[p - 1] == c);
        if (x < Wn - 1) cnt += (pc[p + 1] == c);
        bda = (cnt < 4);   // boundary = img*(5 - (1+cnt)) > 0  <=>  cnt < 4
    }
    if (bm) {
        int cnt = 0;
        if (y > 0)      cnt += (lb[p - Wn] == c);
        if (y < Hn - 1) cnt += (lb[p + Wn] == c);
        if (x > 0)      cnt += (lb[p - 1] == c);
        if (x < Wn - 1) cnt += (lb[p + 1] == c);
        bdb = (cnt < 4);
    }

    int lane = threadIdx.x & 63;
    unsigned long long lower = (1ull << lane) - 1ull;

    unsigned long long ma  = __ballot(a);
    unsigned long long mb  = __ballot(bm);
    unsigned long long mba = __ballot(bda);
    unsigned long long mbb = __ballot(bdb);

    if (lane == 0) {
        if (ma) atomicAdd(&wi[CNT_NA_I(pr)], __popcll(ma));
        if (mb) atomicAdd(&wi[CNT_NB_I(pr)], __popcll(mb));
    }
    // list append: wave leader reserves a chunk, lanes scatter at base+rank
    int base_a = 0, base_b = 0;
    if (lane == 0) {
        if (mba) base_a = atomicAdd(&wi[CNT_BA_I(pr)], __popcll(mba));
        if (mbb) base_b = atomicAdd(&wi[CNT_BB_I(pr)], __popcll(mbb));
    }
    base_a = __shfl(base_a, 0, 64);
    base_b = __shfl(base_b, 0, 64);
    if (bda) wi[BA_OFF + pr * HWn + base_a + __popcll(mba & lower)] = packed;
    if (bdb) wi[BB_OFF + pr * HWn + base_b + __popcll(mbb & lower)] = packed;
}

// Kernel 3: per pair, sum over a_fwd pixels of min-dist to bb list, and over
// b_bwd pixels of min-dist to ba list. Integer d^2 inner loop (exact — matches
// the reference's fp32-exact D2), one sqrtf per active pixel, wave-reduced sum.
__global__ void k_mindist(const int* __restrict__ labels,
                          const int* __restrict__ wi, float* __restrict__ wf) {
    int pr = blockIdx.y;
    int p  = blockIdx.x * blockDim.x + threadIdx.x;   // < HW by grid construction
    int b = pr / Cn, c = pr - b * Cn;
    int a  = (wi[PC_OFF + b * HWn + p] == c);
    int bm = (labels[b * HWn + p] == c);
    int y = p / Wn, x = p - y * Wn;
    int lane = threadIdx.x & 63;

    __shared__ int sc[256];

    // phase 1: a_fwd = a & !bm, min over bb_list
    {
        int nbb = wi[CNT_BB_I(pr)];
        bool active = a && !bm && (nbb > 0);
        int md2 = 0x7fffffff;
        for (int base = 0; base < nbb; base += 256) {
            int n = min(256, nbb - base);
            __syncthreads();
            if ((int)threadIdx.x < n)
                sc[threadIdx.x] = wi[BB_OFF + pr * HWn + base + threadIdx.x];
            __syncthreads();
            if (active) {
                for (int j = 0; j < n; ++j) {
                    int q = sc[j];
                    int dy = y - (q >> 8);
                    int dx = x - (q & 255);
                    md2 = min(md2, dy * dy + dx * dx);
                }
            }
        }
        float v = active ? sqrtf((float)md2) : 0.0f;
#pragma unroll
        for (int off = 32; off >= 1; off >>= 1) v += __shfl_xor(v, off, 64);
        if (lane == 0 && v != 0.0f) atomicAdd(&wf[SUM_F_I(pr)], v);
    }

    // phase 2: b_bwd = bm & !a, min over ba_list
    {
        int nba = wi[CNT_BA_I(pr)];
        bool active = bm && !a && (nba > 0);
        int md2 = 0x7fffffff;
        for (int base = 0; base < nba; base += 256) {
            int n = min(256, nba - base);
            __syncthreads();
            if ((int)threadIdx.x < n)
                sc[threadIdx.x] = wi[BA_OFF + pr * HWn + base + threadIdx.x];
            __syncthreads();
            if (active) {
                for (int j = 0; j < n; ++j) {
                    int q = sc[j];
                    int dy = y - (q >> 8);
                    int dx = x - (q & 255);
                    md2 = min(md2, dy * dy + dx * dx);
                }
            }
        }
        float v = active ? sqrtf((float)md2) : 0.0f;
#pragma unroll
        for (int off = 32; off >= 1; off >>= 1) v += __shfl_xor(v, off, 64);
        if (lane == 0 && v != 0.0f) atomicAdd(&wf[SUM_B_I(pr)], v);
    }
}

// Kernel 4: finalize 25 outputs (single thread; trivial work).
__global__ void k_final(const int* __restrict__ wi, const float* __restrict__ wf,
                        float* __restrict__ out) {
    if (blockIdx.x != 0 || threadIdx.x != 0) return;
    float hd[Bn][Cn];
    float failed[Cn] = {0.f, 0.f, 0.f};
    for (int pr = 0; pr < NP; ++pr) {
        int b = pr / Cn, c = pr - b * Cn;
        int na = wi[CNT_NA_I(pr)];
        int nb = wi[CNT_NB_I(pr)];
        float h;
        if (na == 0) {
            h = (Hn + Wn) / 4.0f;       // failure case
            failed[c] += 1.0f;
        } else {
            float hf = wf[SUM_F_I(pr)] / fmaxf((float)na, 1.0f);
            float hb = wf[SUM_B_I(pr)] / fmaxf((float)nb, 1.0f);
            h = fmaxf(hf, hb);
        }
        if (c == 0) h = 0.0f;           // IGNORE class
        hd[b][c] = h;
    }
    failed[0] = 0.0f;                   // IGNORE class
    for (int b = 0; b < Bn; ++b) {
        float* row = out + b * (Cn + 2);
        float s = 0.f;
        for (int c = 0; c < Cn; ++c) { row[c] = hd[b][c]; s += hd[b][c]; }
        row[Cn] = s / (float)Cn;                               // mean over all C
        row[Cn + 1] = (hd[b][0] + hd[b][1]) / (float)(Cn - 1); // mean over first C-1
    }
    float* Fc = out + Bn * (Cn + 2);
    float fs = 0.f;
    for (int c = 0; c < Cn; ++c) { Fc[c] = failed[c]; fs += failed[c]; }
    Fc[Cn] = fs / (float)Cn;
    Fc[Cn + 1] = (failed[1] + failed[2]) / (float)(Cn - 1);
}

extern "C" void kernel_launch(void* const* d_in, const int* in_sizes, int n_in,
                              void* d_out, int out_size, void* d_ws, size_t ws_size,
                              hipStream_t stream) {
    const float* preds  = (const float*)d_in[0];
    const int*   labels = (const int*)d_in[1];
    float* out = (float*)d_out;
    int*   wi = (int*)d_ws;
    float* wf = (float*)d_ws;

    // 1: zero + argmax  (B*HW = 36864 threads)
    k_prep<<<(Bn * HWn + 255) / 256, 256, 0, stream>>>(preds, wi);
    // 2: boundary + lists  (NP*HW = 110592 threads, wave-aggregated atomics)
    k_boundary<<<(NP * HWn) / 256, 256, 0, stream>>>(labels, wi);
    // 3: min-distance sums  (grid: HW/256 x NP)
    dim3 g3(HWn / 256, NP);
    k_mindist<<<g3, 256, 0, stream>>>(labels, wi, wf);
    // 4: finalize
    k_final<<<1, 64, 0, stream>>>(wi, wf, out);
}

// Round 4
// 126.961 us; speedup vs baseline: 10.3612x; 1.7940x over previous
//
#include <hip/hip_runtime.h>
#include <math.h>

namespace {
constexpr int Bn = 4, Cn = 3, Hn = 96, Wn = 96;
constexpr int HWn = Hn * Wn;          // 9216 (divisible by 256 -> blocks never straddle a pair)
constexpr int NP  = Bn * Cn;          // 12 (batch,class) pairs
constexpr int STRIDE = 16;            // 64B per counter -> each atomic target owns a cacheline

// ws layout in 4-byte words (total ~1.04 MB):
constexpr int PC_OFF  = 0;                    // pred_class [B*HW] int
constexpr int CTR_OFF = Bn * HWn;             // 4 padded arrays x NP x STRIDE
constexpr int CTR_WORDS = 4 * NP * STRIDE;    // 768 words: n_a, n_b, sum_f, sum_b
constexpr int BD_OFF  = CTR_OFF + CTR_WORDS;  // [NP][HW] bit0 = bd_a(pred), bit1 = bd_b(label)
constexpr int G_OFF   = BD_OFF + NP * HWn;    // [NP][HW] packed u16: lo = G_bb (label EDT^2), hi = G_ba (pred EDT^2)

constexpr int SENT = 62500;                   // sentinel d^2 for "no boundary in column" (> 2*9025)

__device__ __forceinline__ int CNT_NA_I(int pr) { return CTR_OFF + (0 * NP + pr) * STRIDE; }
__device__ __forceinline__ int CNT_NB_I(int pr) { return CTR_OFF + (1 * NP + pr) * STRIDE; }
__device__ __forceinline__ int SUM_F_I(int pr)  { return CTR_OFF + (2 * NP + pr) * STRIDE; }
__device__ __forceinline__ int SUM_B_I(int pr)  { return CTR_OFF + (3 * NP + pr) * STRIDE; }
}

// Kernel 1: zero counters/sums + per-pixel argmax over C classes.
__global__ void k_prep(const float* __restrict__ preds, int* __restrict__ wi) {
    int idx = blockIdx.x * blockDim.x + threadIdx.x;
    if (idx < CTR_WORDS) wi[CTR_OFF + idx] = 0;      // zeros ints AND f32 sums (bit pattern 0)
    if (idx >= Bn * HWn) return;
    int b = idx / HWn, p = idx - b * HWn;
    const float* base = preds + (size_t)b * Cn * HWn + p;
    float best = base[0];
    int bi = 0;
#pragma unroll
    for (int c = 1; c < Cn; ++c) {
        float v = base[(size_t)c * HWn];
        if (v > best) { best = v; bi = c; }          // strict > == jnp.argmax first-max
    }
    wi[PC_OFF + idx] = bi;
}

// Kernel 2: membership counts (wave-aggregated atomics) + boundary flags.
// boundary = img*(5-new) > 0  <=>  in-mask && (#in-bounds in-mask neighbors) < 4.
__global__ void k_boundary(const int* __restrict__ labels, int* __restrict__ wi) {
    int idx = blockIdx.x * blockDim.x + threadIdx.x;   // < NP*HW by grid construction
    int pr = idx / HWn, p = idx - pr * HWn;            // pr uniform per block (HW % 256 == 0)
    int b = pr / Cn, c = pr - b * Cn;
    int y = p / Wn, x = p - y * Wn;
    const int* pc = wi + PC_OFF + b * HWn;
    const int* lb = labels + b * HWn;
    int a  = (pc[p] == c);
    int bm = (lb[p] == c);

    int bda = 0, bdb = 0;
    if (a) {
        int cnt = 0;
        if (y > 0)      cnt += (pc[p - Wn] == c);
        if (y < Hn - 1) cnt += (pc[p + Wn] == c);
        if (x > 0)      cnt += (pc[p - 1] == c);
        if (x < Wn - 1) cnt += (pc[p + 1] == c);
        bda = (cnt < 4);
    }
    if (bm) {
        int cnt = 0;
        if (y > 0)      cnt += (lb[p - Wn] == c);
        if (y < Hn - 1) cnt += (lb[p + Wn] == c);
        if (x > 0)      cnt += (lb[p - 1] == c);
        if (x < Wn - 1) cnt += (lb[p + 1] == c);
        bdb = (cnt < 4);
    }
    wi[BD_OFF + pr * HWn + p] = bda | (bdb << 1);

    int lane = threadIdx.x & 63;
    unsigned long long ma = __ballot(a);
    unsigned long long mb = __ballot(bm);
    if (lane == 0) {
        if (ma) atomicAdd(&wi[CNT_NA_I(pr)], __popcll(ma));
        if (mb) atomicAdd(&wi[CNT_NB_I(pr)], __popcll(mb));
    }
}

// Kernel 3: EDT pass 1 — per (pair, column), 1D nearest-boundary distance via
// forward+backward sweeps over y, for BOTH masks at once. Final word per pixel:
// lo16 = min_by (y-by)^2 over label-boundary (bd_b), hi16 = same over pred-boundary
// (bd_a); SENT if the column has no boundary pixel of that mask.
__global__ void k_edt_cols(int* __restrict__ wi) {
    int t = blockIdx.x * blockDim.x + threadIdx.x;
    if (t >= NP * Wn) return;
    int pr = t / Wn, x = t - pr * Wn;
    const int* bd = wi + BD_OFF + pr * HWn;
    int* g = wi + G_OFF + pr * HWn;

    // forward sweep: store (da_fwd | db_fwd<<16), capped at 200
    int da = 200, db = 200;
    for (int y = 0; y < Hn; ++y) {
        int w = bd[y * Wn + x];
        da = (w & 1) ? 0 : min(da + 1, 200);
        db = (w & 2) ? 0 : min(db + 1, 200);
        g[y * Wn + x] = da | (db << 16);
    }
    // backward sweep: combine, square, sentinel, repack (lo = label/bd_b!)
    da = 200; db = 200;
    for (int y = Hn - 1; y >= 0; --y) {
        int w = bd[y * Wn + x];
        da = (w & 1) ? 0 : min(da + 1, 200);
        db = (w & 2) ? 0 : min(db + 1, 200);
        int f = g[y * Wn + x];
        int fa = min(f & 0xffff, da);       // pred-boundary 1D dist
        int fb = min(f >> 16, db);          // label-boundary 1D dist
        int sa = (fa >= Hn) ? SENT : fa * fa;
        int sb = (fb >= Hn) ? SENT : fb * fb;
        g[y * Wn + x] = sb | (sa << 16);    // lo16 = G_bb (label), hi16 = G_ba (pred)
    }
}

// Kernel 4: EDT pass 2 fused with the masked sum. Per pixel: if pred-only
// (and labels nonempty) take min over x' of G_bb(y,x') + (x-x')^2; if
// label-only (and preds nonempty) same over G_ba. One sqrtf, wave-reduced sums.
__global__ void k_sum(const int* __restrict__ labels,
                      const int* __restrict__ wi, float* __restrict__ wf) {
    int idx = blockIdx.x * blockDim.x + threadIdx.x;   // < NP*HW
    int pr = idx / HWn, p = idx - pr * HWn;
    int b = pr / Cn, c = pr - b * Cn;
    int a  = (wi[PC_OFF + b * HWn + p] == c);
    int bm = (labels[b * HWn + p] == c);
    int na = wi[CNT_NA_I(pr)];
    int nb = wi[CNT_NB_I(pr)];
    // nonempty mask <=> nonempty boundary (edge pixels have <4 in-bounds nbrs)
    bool af = a && !bm && (nb > 0);    // pred-only pixel -> dist to label boundary
    bool bw = bm && !a && (na > 0);    // label-only pixel -> dist to pred boundary
    int y = p / Wn, x = p - y * Wn;
    const int* grow = wi + G_OFF + pr * HWn + y * Wn;

    float s = 0.0f;
    if (af || bw) {
        int sh = af ? 0 : 16;
        int md2 = 0x7fffffff;
#pragma unroll 8
        for (int xp = 0; xp < Wn; ++xp) {
            int gs = (grow[xp] >> sh) & 0xffff;
            int dx = x - xp;
            md2 = min(md2, gs + dx * dx);
        }
        s = sqrtf((float)md2);     // md2 integer <= 18050: fp32-exact, matches reference
    }
    float vF = af ? s : 0.0f;
    float vB = bw ? s : 0.0f;
#pragma unroll
    for (int off = 32; off >= 1; off >>= 1) {
        vF += __shfl_xor(vF, off, 64);
        vB += __shfl_xor(vB, off, 64);
    }
    int lane = threadIdx.x & 63;
    if (lane == 0) {
        if (vF != 0.0f) atomicAdd(&wf[SUM_F_I(pr)], vF);
        if (vB != 0.0f) atomicAdd(&wf[SUM_B_I(pr)], vB);
    }
}

// Kernel 5: finalize 25 outputs (single thread; trivial work).
__global__ void k_final(const int* __restrict__ wi, const float* __restrict__ wf,
                        float* __restrict__ out) {
    if (blockIdx.x != 0 || threadIdx.x != 0) return;
    float hd[Bn][Cn];
    float failed[Cn] = {0.f, 0.f, 0.f};
    for (int pr = 0; pr < NP; ++pr) {
        int b = pr / Cn, c = pr - b * Cn;
        int na = wi[CNT_NA_I(pr)];
        int nb = wi[CNT_NB_I(pr)];
        float h;
        if (na == 0) {
            h = (Hn + Wn) / 4.0f;       // failure case
            failed[c] += 1.0f;
        } else {
            float hf = wf[SUM_F_I(pr)] / fmaxf((float)na, 1.0f);
            float hb = wf[SUM_B_I(pr)] / fmaxf((float)nb, 1.0f);
            h = fmaxf(hf, hb);
        }
        if (c == 0) h = 0.0f;           // IGNORE class
        hd[b][c] = h;
    }
    failed[0] = 0.0f;                   // IGNORE class
    for (int b = 0; b < Bn; ++b) {
        float* row = out + b * (Cn + 2);
        float s = 0.f;
        for (int c = 0; c < Cn; ++c) { row[c] = hd[b][c]; s += hd[b][c]; }
        row[Cn] = s / (float)Cn;                               // mean over all C
        row[Cn + 1] = (hd[b][0] + hd[b][1]) / (float)(Cn - 1); // mean over first C-1
    }
    float* Fc = out + Bn * (Cn + 2);
    float fs = 0.f;
    for (int c = 0; c < Cn; ++c) { Fc[c] = failed[c]; fs += failed[c]; }
    Fc[Cn] = fs / (float)Cn;
    Fc[Cn + 1] = (failed[1] + failed[2]) / (float)(Cn - 1);
}

extern "C" void kernel_launch(void* const* d_in, const int* in_sizes, int n_in,
                              void* d_out, int out_size, void* d_ws, size_t ws_size,
                              hipStream_t stream) {
    const float* preds  = (const float*)d_in[0];
    const int*   labels = (const int*)d_in[1];
    float* out = (float*)d_out;
    int*   wi = (int*)d_ws;
    float* wf = (float*)d_ws;

    // 1: zero + argmax  (B*HW = 36864 threads)
    k_prep<<<(Bn * HWn + 255) / 256, 256, 0, stream>>>(preds, wi);
    // 2: boundary flags + counts  (NP*HW = 110592 threads)
    k_boundary<<<(NP * HWn) / 256, 256, 0, stream>>>(labels, wi);
    // 3: EDT pass 1, column sweeps  (NP*W = 1152 threads)
    k_edt_cols<<<(NP * Wn + 255) / 256, 256, 0, stream>>>(wi);
    // 4: EDT pass 2 + masked sums  (NP*HW threads)
    k_sum<<<(NP * HWn) / 256, 256, 0, stream>>>(labels, wi, wf);
    // 5: finalize
    k_final<<<1, 64, 0, stream>>>(wi, wf, out);
}

// Round 5
// 77.650 us; speedup vs baseline: 16.9412x; 1.6351x over previous
//
#include <hip/hip_runtime.h>
#include <math.h>

namespace {
constexpr int Bn = 4, Cn = 3, Hn = 96, Wn = 96;
constexpr int HWn = Hn * Wn;          // 9216 (divisible by 256)
constexpr int NP  = Bn * Cn;          // 12 (batch,class) pairs
constexpr int STRIDE = 16;            // 64B per counter -> each atomic target owns a cacheline

// ws layout in 4-byte words (total ~620 KB):
constexpr int PC_OFF  = 0;                    // pred_class [B*HW] int
constexpr int CTR_OFF = Bn * HWn;             // 4 padded arrays x NP x STRIDE
constexpr int CTR_WORDS = 4 * NP * STRIDE;    // n_a, n_b, sum_f, sum_b
constexpr int BD_OFF  = CTR_OFF + CTR_WORDS;  // [NP][HW] bit0 = bd_a(pred), bit1 = bd_b(label)
constexpr int MK_OFF  = BD_OFF + NP * HWn;    // [NP][6][96] u32 column bitmasks (w0..2 = bd_a, w3..5 = bd_b)

constexpr int SENT = 62500;                   // "no boundary in column" d^2 (> 9025+9025)

__device__ __forceinline__ int CNT_NA_I(int pr) { return CTR_OFF + (0 * NP + pr) * STRIDE; }
__device__ __forceinline__ int CNT_NB_I(int pr) { return CTR_OFF + (1 * NP + pr) * STRIDE; }
__device__ __forceinline__ int SUM_F_I(int pr)  { return CTR_OFF + (2 * NP + pr) * STRIDE; }
__device__ __forceinline__ int SUM_B_I(int pr)  { return CTR_OFF + (3 * NP + pr) * STRIDE; }
}

// Kernel 1: zero counters/sums + per-pixel argmax over C classes.
__global__ void k_prep(const float* __restrict__ preds, int* __restrict__ wi) {
    int idx = blockIdx.x * blockDim.x + threadIdx.x;
    if (idx < CTR_WORDS) wi[CTR_OFF + idx] = 0;      // zeros ints AND f32 sums (bit pattern 0)
    if (idx >= Bn * HWn) return;
    int b = idx / HWn, p = idx - b * HWn;
    const float* base = preds + (size_t)b * Cn * HWn + p;
    float best = base[0];
    int bi = 0;
#pragma unroll
    for (int c = 1; c < Cn; ++c) {
        float v = base[(size_t)c * HWn];
        if (v > best) { best = v; bi = c; }          // strict > == jnp.argmax first-max
    }
    wi[PC_OFF + idx] = bi;
}

// Kernel 2: membership counts (wave-aggregated atomics) + boundary flags.
// boundary = img*(5-new) > 0  <=>  in-mask && (#in-bounds in-mask neighbors) < 4.
__global__ void k_boundary(const int* __restrict__ labels, int* __restrict__ wi) {
    int idx = blockIdx.x * blockDim.x + threadIdx.x;   // < NP*HW by grid construction
    int pr = idx / HWn, p = idx - pr * HWn;            // pr uniform per block (HW % 256 == 0)
    int b = pr / Cn, c = pr - b * Cn;
    int y = p / Wn, x = p - y * Wn;
    const int* pc = wi + PC_OFF + b * HWn;
    const int* lb = labels + b * HWn;
    int a  = (pc[p] == c);
    int bm = (lb[p] == c);

    int bda = 0, bdb = 0;
    if (a) {
        int cnt = 0;
        if (y > 0)      cnt += (pc[p - Wn] == c);
        if (y < Hn - 1) cnt += (pc[p + Wn] == c);
        if (x > 0)      cnt += (pc[p - 1] == c);
        if (x < Wn - 1) cnt += (pc[p + 1] == c);
        bda = (cnt < 4);
    }
    if (bm) {
        int cnt = 0;
        if (y > 0)      cnt += (lb[p - Wn] == c);
        if (y < Hn - 1) cnt += (lb[p + Wn] == c);
        if (x > 0)      cnt += (lb[p - 1] == c);
        if (x < Wn - 1) cnt += (lb[p + 1] == c);
        bdb = (cnt < 4);
    }
    wi[BD_OFF + pr * HWn + p] = bda | (bdb << 1);

    int lane = threadIdx.x & 63;
    unsigned long long ma = __ballot(a);
    unsigned long long mb = __ballot(bm);
    if (lane == 0) {
        if (ma) atomicAdd(&wi[CNT_NA_I(pr)], __popcll(ma));
        if (mb) atomicAdd(&wi[CNT_NB_I(pr)], __popcll(mb));
    }
}

// Kernel 3: build per-column boundary bitmasks. Thread = (pair, word, col):
// 32 independent strided reads (coalesced across lanes), no recurrence.
__global__ void k_masks(int* __restrict__ wi) {
    int t = blockIdx.x * blockDim.x + threadIdx.x;
    if (t >= NP * 288) return;
    int pr = t / 288, rem = t - pr * 288;
    int w = rem / 96, x = rem - w * 96;
    const int* bd = wi + BD_OFF + pr * HWn;
    unsigned int am = 0, bm = 0;
#pragma unroll
    for (int k = 0; k < 32; ++k) {
        int f = bd[(w * 32 + k) * Wn + x];
        am |= (unsigned)(f & 1) << k;
        bm |= (unsigned)((f >> 1) & 1) << k;
    }
    wi[MK_OFF + pr * 576 + w * 96 + x]       = (int)am;
    wi[MK_OFF + pr * 576 + (w + 3) * 96 + x] = (int)bm;
}

// Kernel 4: fused EDT pass1 (bitmask nearest-set-bit, O(1) per value) +
// pass2 (min over x' of G + dx^2, exact integers) + masked sqrt sums.
// Block = (pair, 4-row band), 384 threads.
__global__ void k_edt_sum(const int* __restrict__ labels,
                          const int* __restrict__ wi, float* __restrict__ wf) {
    int pr = blockIdx.y;
    int rb = blockIdx.x;            // 0..23
    int j  = threadIdx.x;           // 0..383
    int b = pr / Cn, c = pr - b * Cn;

    __shared__ unsigned int mlds[576];   // [6][96] column mask words
    __shared__ unsigned int glds[384];   // [4][96] packed u16: lo=G_bb(label), hi=G_ba(pred)

    for (int k = j; k < 576; k += 384)
        mlds[k] = (unsigned int)wi[MK_OFF + pr * 576 + k];
    __syncthreads();

    int r = j / 96, xp = j - r * 96;     // this thread's (row-in-band, column)
    int y = rb * 4 + r;

    // 128-bit column masks (bits 0..95)
    unsigned long long alo = (unsigned long long)mlds[xp]
                           | ((unsigned long long)mlds[96 + xp] << 32);
    unsigned long long ahi = mlds[192 + xp];
    unsigned long long blo = (unsigned long long)mlds[288 + xp]
                           | ((unsigned long long)mlds[384 + xp] << 32);
    unsigned long long bhi = mlds[480 + xp];

    __uint128_t Ma = ((__uint128_t)ahi << 64) | alo;   // pred boundary
    __uint128_t Mb = ((__uint128_t)bhi << 64) | blo;   // label boundary

    auto dist1d = [&](__uint128_t M) -> int {
        int du = 200, dd = 200;
        __uint128_t s = M >> y;                        // bits at rows >= y
        if (s) {
            unsigned long long l = (unsigned long long)s;
            du = l ? __builtin_ctzll(l) : 64 + __builtin_ctzll((unsigned long long)(s >> 64));
        }
        s = M << (127 - y);                            // bit y lands at position 127
        if (s) {
            unsigned long long h = (unsigned long long)(s >> 64);
            dd = h ? __builtin_clzll(h) : 64 + __builtin_clzll((unsigned long long)s);
        }
        int d = min(du, dd);
        return (d >= Hn) ? SENT : d * d;
    };
    glds[j] = (unsigned)dist1d(Mb) | ((unsigned)dist1d(Ma) << 16);
    __syncthreads();

    // pass 2 for pixel (y, x = xp)
    int x = xp, p = y * Wn + x;
    int a   = (wi[PC_OFF + b * HWn + p] == c);
    int bmf = (labels[b * HWn + p] == c);
    int na = wi[CNT_NA_I(pr)];
    int nb = wi[CNT_NB_I(pr)];
    // nonempty mask <=> nonempty boundary (edge pixels have <4 in-bounds nbrs)
    bool af = a && !bmf && (nb > 0);     // pred-only -> dist to label boundary (lo16)
    bool bw = bmf && !a && (na > 0);     // label-only -> dist to pred boundary (hi16)

    float s = 0.0f;
    if (af || bw) {
        int sh = af ? 0 : 16;
        int md2 = 0x7fffffff;
        const unsigned int* grow = &glds[r * 96];
#pragma unroll 8
        for (int q = 0; q < Wn; ++q) {
            int gs = (grow[q] >> sh) & 0xffff;
            int dx = x - q;
            md2 = min(md2, gs + dx * dx);
        }
        s = sqrtf((float)md2);   // integer md2 <= 18050: fp32-exact, matches reference
    }
    float vF = af ? s : 0.0f;
    float vB = bw ? s : 0.0f;
#pragma unroll
    for (int off = 32; off >= 1; off >>= 1) {
        vF += __shfl_xor(vF, off, 64);
        vB += __shfl_xor(vB, off, 64);
    }
    if ((j & 63) == 0) {
        if (vF != 0.0f) atomicAdd(&wf[SUM_F_I(pr)], vF);
        if (vB != 0.0f) atomicAdd(&wf[SUM_B_I(pr)], vB);
    }
}

// Kernel 5: finalize 25 outputs (single thread; trivial work).
__global__ void k_final(const int* __restrict__ wi, const float* __restrict__ wf,
                        float* __restrict__ out) {
    if (blockIdx.x != 0 || threadIdx.x != 0) return;
    float hd[Bn][Cn];
    float failed[Cn] = {0.f, 0.f, 0.f};
    for (int pr = 0; pr < NP; ++pr) {
        int b = pr / Cn, c = pr - b * Cn;
        int na = wi[CNT_NA_I(pr)];
        int nb = wi[CNT_NB_I(pr)];
        float h;
        if (na == 0) {
            h = (Hn + Wn) / 4.0f;       // failure case
            failed[c] += 1.0f;
        } else {
            float hf = wf[SUM_F_I(pr)] / fmaxf((float)na, 1.0f);
            float hb = wf[SUM_B_I(pr)] / fmaxf((float)nb, 1.0f);
            h = fmaxf(hf, hb);
        }
        if (c == 0) h = 0.0f;           // IGNORE class
        hd[b][c] = h;
    }
    failed[0] = 0.0f;                   // IGNORE class
    for (int b = 0; b < Bn; ++b) {
        float* row = out + b * (Cn + 2);
        float s = 0.f;
        for (int c = 0; c < Cn; ++c) { row[c] = hd[b][c]; s += hd[b][c]; }
        row[Cn] = s / (float)Cn;                               // mean over all C
        row[Cn + 1] = (hd[b][0] + hd[b][1]) / (float)(Cn - 1); // mean over first C-1
    }
    float* Fc = out + Bn * (Cn + 2);
    float fs = 0.f;
    for (int c = 0; c < Cn; ++c) { Fc[c] = failed[c]; fs += failed[c]; }
    Fc[Cn] = fs / (float)Cn;
    Fc[Cn + 1] = (failed[1] + failed[2]) / (float)(Cn - 1);
}

extern "C" void kernel_launch(void* const* d_in, const int* in_sizes, int n_in,
                              void* d_out, int out_size, void* d_ws, size_t ws_size,
                              hipStream_t stream) {
    const float* preds  = (const float*)d_in[0];
    const int*   labels = (const int*)d_in[1];
    float* out = (float*)d_out;
    int*   wi = (int*)d_ws;
    float* wf = (float*)d_ws;

    // 1: zero + argmax  (B*HW = 36864 threads)
    k_prep<<<(Bn * HWn + 255) / 256, 256, 0, stream>>>(preds, wi);
    // 2: boundary flags + counts  (NP*HW = 110592 threads)
    k_boundary<<<(NP * HWn) / 256, 256, 0, stream>>>(labels, wi);
    // 3: column bitmasks  (NP*288 = 3456 threads)
    k_masks<<<(NP * 288 + 255) / 256, 256, 0, stream>>>(wi);
    // 4: fused EDT + masked sums  (grid 24 x NP, 384 threads)
    dim3 g4(Hn / 4, NP);
    k_edt_sum<<<g4, 384, 0, stream>>>(labels, wi, wf);
    // 5: finalize
    k_final<<<1, 64, 0, stream>>>(wi, wf, out);
}